// Round 12
// baseline (2163.987 us; speedup 1.0000x reference)
//
#include <hip/hip_runtime.h>

#define NN 4096
#define BN 32768

typedef __attribute__((ext_vector_type(8))) short short8;
typedef __attribute__((ext_vector_type(4))) float f32x4;

__device__ __forceinline__ float sigmoidf_(float x){ return 1.f/(1.f+__expf(-x)); }
__device__ __forceinline__ unsigned short bfr(float f){
    unsigned int u = __float_as_uint(f);
    u += 0x7FFFu + ((u>>16)&1u);
    return (unsigned short)(u>>16);
}
__device__ __forceinline__ float b2f(unsigned short h){
    return __uint_as_float(((unsigned int)h)<<16);
}

// ---- prep: As/Ad, cE, AsAdT[16][64] bf16, WT2 hi/lo [64 j][256 khh] bf16 ----
__global__ void prep_kernel(const float* __restrict__ W_gat,
                            const float* __restrict__ att_src,
                            const float* __restrict__ att_dst,
                            const float* __restrict__ W_edge,
                            const float* __restrict__ att_edge,
                            float* __restrict__ As, float* __restrict__ Ad,
                            float* __restrict__ cE,
                            unsigned short* __restrict__ AsAdT,
                            unsigned short* __restrict__ WT2h,
                            unsigned short* __restrict__ WT2l)
{
    int t = threadIdx.x;          // 256
    int i = t >> 2, hh = t & 3;   // t = k*4+h
    float s = 0.f, d = 0.f;
    for (int j = 0; j < 64; j++){
        float w = W_gat[i*256 + hh*64 + j];
        s += w * att_src[hh*64 + j];
        d += w * att_dst[hh*64 + j];
    }
    As[t] = s;
    Ad[t] = d;
    if (t < 12){
        int e = t >> 2, h2 = t & 3;
        float cc = 0.f;
        for (int k = 0; k < 64; k++)
            cc += W_edge[e*256 + h2*64 + k] * att_edge[h2*64 + k];
        cE[h2*3 + e] = cc;
    }
    __syncthreads();
    if (t < 16){
        for (int k = 0; k < 64; k++){
            float v = (t < 4) ? As[k*4 + t] : (t < 8 ? Ad[k*4 + (t-4)] : 0.f);
            AsAdT[t*64 + k] = bfr(v);
        }
    }
    {
        int j = t >> 2, q = t & 3;
        for (int k = 0; k < 64; k++){
            float wv = W_gat[k*256 + q*64 + j];
            unsigned short hi = bfr(wv);
            WT2h[j*256 + q*64 + k] = hi;
            WT2l[j*256 + q*64 + k] = bfr(wv - b2f(hi));
        }
    }
}

// ---- encoder: block = 64 consecutive nodes, lane = node; HX bf16 out ----
__global__ __launch_bounds__(256) void enc_kernel(
    const float* __restrict__ x,
    const float* __restrict__ W1, const float* __restrict__ b1,
    const float* __restrict__ W2, const float* __restrict__ b2,
    unsigned short* __restrict__ HX)
{
    __shared__ __align__(16) float sm[5168];
    float* xT  = sm;          // [12][68]
    float* t1  = sm + 816;    // [64][68]

    int t = threadIdx.x;
    int w = __builtin_amdgcn_readfirstlane(t >> 6);
    int lane = t & 63;
    int n0 = blockIdx.x * 64;
    int b = n0 >> 12;
    int cell0 = n0 & 4095;

    for (int e = t; e < 12*64; e += 256){
        int c = e >> 6, u = e & 63;
        xT[c*68 + u] = x[b*(12*NN) + c*NN + cell0 + u];
    }
    __syncthreads();

    #pragma unroll
    for (int jj = 0; jj < 16; jj++){
        int j = w*16 + jj;
        float a = b1[j];
        #pragma unroll
        for (int c = 0; c < 12; c++)
            a += xT[c*68 + lane] * W1[c*64 + j];
        t1[j*68 + lane] = a * sigmoidf_(a);
    }
    __syncthreads();

    float hk[16];
    #pragma unroll
    for (int kk = 0; kk < 16; kk++) hk[kk] = b2[w*16 + kk];
    for (int j = 0; j < 64; j++){
        float v = t1[j*68 + lane];
        #pragma unroll
        for (int kk = 0; kk < 16; kk++)
            hk[kk] += v * W2[j*64 + w*16 + kk];
    }
    int hb = (n0 + lane)*64 + w*16;
    unsigned int* dst = (unsigned int*)&HX[hb];
    #pragma unroll
    for (int p = 0; p < 8; p++)
        dst[p] = (unsigned int)bfr(hk[2*p]) | ((unsigned int)bfr(hk[2*p+1])<<16);
}

// ================== step_kernel: one FULL RK4 step (4 stages) ==================
// block = 8x8 tile + halo-4 (16x16 staged region); 256 threads / 4 waves.
// All intermediate state in LDS/registers; global: HX read (halo) + HX write (own).
__global__ __launch_bounds__(256, 2) void step_kernel(
    const unsigned short* __restrict__ HIN,   // [BN][64] bf16
    unsigned short* __restrict__ HOUT,        // [BN][64] bf16
    const float* __restrict__ x,
    const float* __restrict__ CCE,
    const unsigned short* __restrict__ AsAdT,
    const unsigned short* __restrict__ WT2h, const unsigned short* __restrict__ WT2l,
    const float* __restrict__ b_gat, const float* __restrict__ g_f, const float* __restrict__ bt_f)
{
    __shared__ __align__(16) char smem[78336];
    unsigned short* hCur = (unsigned short*)smem;            // [256][72] bf16
    unsigned short* hB   = (unsigned short*)(smem + 36864);  // [224][72] bf16 (rows 1..14)
    float* as2 = (float*)(smem + 69120);                     // [256][4]
    float* ad2 = (float*)(smem + 73216);                     // [256][4]
    float* x0h = (float*)(smem + 77312);                     // [256]

    int t = threadIdx.x;
    int w = __builtin_amdgcn_readfirstlane(t >> 6);
    int lane = t & 63;
    int l15 = lane & 15, lg = lane >> 4;
    int blk = blockIdx.x;
    int b = blk & 7, tile = blk >> 3;      // batch pinned to XCD
    int tr = tile >> 3, tc = tile & 7;
    int r0 = tr*8 - 4, c0 = tc*8 - 4;      // halo-4 origin
    int nb = b*NN;
    int xb = b*(12*NN);

    const int DYI[8] = {-1,-1,-1,0,0,1,1,1};
    const int DXI[8] = {-1,0,1,-1,1,-1,0,1};
    const float s2c = 0.70710678f;
    const float DXN[8] = {-s2c,0.f,s2c,-1.f,1.f,-s2c,0.f,s2c};
    const float DYN[8] = {-s2c,-1.f,-s2c,0.f,0.f,s2c,1.f,s2c};

    // ---- phase 0: stage halo-4 region (bf16) into hCur + hB; x0h ----
    for (int u = t; u < 2048; u += 256){
        int m = u >> 3, k8 = u & 7;
        int hr = m >> 4, hc = m & 15;
        int r = min(63, max(0, r0 + hr)), c = min(63, max(0, c0 + hc));
        uint4 v = *(const uint4*)&HIN[(long)(nb + r*64 + c)*64 + k8*8];
        *(uint4*)&hCur[m*72 + k8*8] = v;
        if (hr >= 1 && hr <= 14) *(uint4*)&hB[(m-16)*72 + k8*8] = v;
        if (k8 == 0) x0h[m] = x[xb + r*64 + c];
    }

    // hoisted constants
    float ce[12];
    #pragma unroll
    for (int q = 0; q < 12; q++) ce[q] = CCE[q];
    float bg[4], gf[4], bf_[4];
    #pragma unroll
    for (int nt = 0; nt < 4; nt++){
        int j = nt*16 + l15;
        bg[nt] = b_gat[j]; gf[nt] = g_f[j]; bf_[nt] = bt_f[j];
    }

    float kv[4][16];    // deferred k per group [g][reg*4+nt]
    float Ast[2][16];   // RK4 accumulator, radius-0 groups g=1,2

    for (int s = 0; s < 4; s++){
        __syncthreads();   // hCur stable (staging or previous update)

        // ---- A: as/ad via MFMA over all 256 nodes (16 tiles / 4 waves) ----
        #pragma unroll
        for (int tt = 0; tt < 4; tt++){
            int tileN = tt*4 + w;
            f32x4 acc = {0.f,0.f,0.f,0.f};
            #pragma unroll
            for (int kt = 0; kt < 2; kt++){
                short8 afr  = *(const short8*)&AsAdT[l15*64 + kt*32 + lg*8];
                short8 bfrg = *(const short8*)&hCur[(tileN*16+l15)*72 + kt*32 + lg*8];
                acc = __builtin_amdgcn_mfma_f32_16x16x32_bf16(afr, bfrg, acc, 0,0,0);
            }
            int m = tileN*16 + l15;
            if (lg == 0)      *(float4*)&as2[m*4] = make_float4(acc[0],acc[1],acc[2],acc[3]);
            else if (lg == 1) *(float4*)&ad2[m*4] = make_float4(acc[0],acc[1],acc[2],acc[3]);
        }
        __syncthreads();

        int lo = s + 1, hi = 14 - s;

        // ---- B: group loop (rows g*4+w), alpha in-reg + mix + GEMM + LN ----
        #pragma unroll
        for (int g = 0; g < 4; g++){
            int hrE = g*4 + w;                 // wave-uniform eval row
            if (hrE >= lo && hrE <= hi){
                int me = hrE*16 + l15;         // eval node (col = l15)
                int gr = r0 + hrE, gc = c0 + l15;
                float x0n = x0h[me];

                float al[4][8];
                #pragma unroll
                for (int hh = 0; hh < 4; hh++){
                    float adv = ad2[me*4 + hh];
                    float mx = -1e30f;
                    #pragma unroll
                    for (int o = 0; o < 8; o++){
                        int mr = gr - DYI[o], mc = gc - DXI[o];
                        bool vld = (mr>=0)&&(mr<64)&&(mc>=0)&&(mc<64);
                        int hm = me - DYI[o]*16 - DXI[o];
                        float a = as2[hm*4+hh] + adv + ce[hh*3+0]*DXN[o] + ce[hh*3+1]*DYN[o]
                                + ce[hh*3+2]*(x0n - x0h[hm]);
                        a = (a >= 0.f) ? a : 0.2f*a;
                        al[hh][o] = vld ? a : -1e30f;
                        mx = fmaxf(mx, al[hh][o]);
                    }
                    float z = 0.f;
                    #pragma unroll
                    for (int o = 0; o < 8; o++){
                        float p = (al[hh][o] > -1e29f) ? __expf(al[hh][o]-mx) : 0.f;
                        al[hh][o] = p; z += p;
                    }
                    float zi = 1.f/(z + 1e-16f);
                    #pragma unroll
                    for (int o = 0; o < 8; o++) al[hh][o] *= zi;
                }

                // mix into A-fragment layout
                float G[8][8];
                #pragma unroll
                for (int kt = 0; kt < 8; kt++)
                    #pragma unroll
                    for (int i = 0; i < 8; i++) G[kt][i] = 0.f;
                #pragma unroll
                for (int o = 0; o < 8; o++){
                    int hm = me - DYI[o]*16 - DXI[o];
                    const unsigned short* hp8 = &hCur[hm*72 + lg*8];
                    short8 v0 = *(const short8*)&hp8[0];
                    short8 v1 = *(const short8*)&hp8[32];
                    float a0 = al[0][o], a1 = al[1][o], a2 = al[2][o], a3 = al[3][o];
                    #pragma unroll
                    for (int i = 0; i < 8; i++){
                        float f0 = b2f((unsigned short)v0[i]);
                        float f1 = b2f((unsigned short)v1[i]);
                        G[0][i] += a0*f0;  G[1][i] += a0*f1;
                        G[2][i] += a1*f0;  G[3][i] += a1*f1;
                        G[4][i] += a2*f0;  G[5][i] += a2*f1;
                        G[6][i] += a3*f0;  G[7][i] += a3*f1;
                    }
                }

                // stacked GEMM (A regs, B = WT2 hi/lo)
                f32x4 oacc[4];
                #pragma unroll
                for (int nt = 0; nt < 4; nt++) oacc[nt] = (f32x4){0.f,0.f,0.f,0.f};
                #pragma unroll
                for (int kt = 0; kt < 8; kt++){
                    short8 afr;
                    #pragma unroll
                    for (int i = 0; i < 8; i++) afr[i] = (short)bfr(G[kt][i]);
                    #pragma unroll
                    for (int nt = 0; nt < 4; nt++){
                        short8 bh = *(const short8*)&WT2h[(nt*16+l15)*256 + kt*32 + lg*8];
                        oacc[nt] = __builtin_amdgcn_mfma_f32_16x16x32_bf16(afr, bh, oacc[nt], 0,0,0);
                    }
                    #pragma unroll
                    for (int nt = 0; nt < 4; nt++){
                        short8 bl = *(const short8*)&WT2l[(nt*16+l15)*256 + kt*32 + lg*8];
                        oacc[nt] = __builtin_amdgcn_mfma_f32_16x16x32_bf16(afr, bl, oacc[nt], 0,0,0);
                    }
                }

                // LN + silu -> kv (deferred); Ast for radius-0 groups
                #pragma unroll
                for (int reg = 0; reg < 4; reg++){
                    float vv[4];
                    float s1 = 0.f, s2 = 0.f;
                    #pragma unroll
                    for (int nt = 0; nt < 4; nt++){
                        float v = oacc[nt][reg]*0.25f + bg[nt];
                        vv[nt] = v; s1 += v; s2 += v*v;
                    }
                    s1 += __shfl_xor(s1,1); s2 += __shfl_xor(s2,1);
                    s1 += __shfl_xor(s1,2); s2 += __shfl_xor(s2,2);
                    s1 += __shfl_xor(s1,4); s2 += __shfl_xor(s2,4);
                    s1 += __shfl_xor(s1,8); s2 += __shfl_xor(s2,8);
                    float mean = s1*(1.f/64.f);
                    float var  = s2*(1.f/64.f) - mean*mean;
                    float rstd = rsqrtf(fmaxf(var,0.f) + 1e-5f);
                    #pragma unroll
                    for (int nt = 0; nt < 4; nt++){
                        float y = (vv[nt]-mean)*rstd*gf[nt] + bf_[nt];
                        float kk = y * sigmoidf_(y);
                        kv[g][reg*4+nt] = kk;
                        if ((g == 1 || g == 2) && (lg == 1 || lg == 2)){
                            if (s == 0)      Ast[g-1][reg*4+nt]  = kk;
                            else if (s < 3)  Ast[g-1][reg*4+nt] += 2.f*kk;
                        }
                    }
                }
            }
        }
        __syncthreads();   // all hCur reads done before updates

        // ---- D: rebuild next stage input hCur = hB + c*kv (or final -> HOUT) ----
        float cs = (s == 2) ? 0.25f : 0.125f;
        #pragma unroll
        for (int g = 0; g < 4; g++){
            int hr3 = g*4 + w;
            if (s < 3){
                if (hr3 >= lo && hr3 <= hi){
                    #pragma unroll
                    for (int reg = 0; reg < 4; reg++){
                        int hc3 = lg*4 + reg;
                        if (hc3 >= lo && hc3 <= hi){
                            int e3 = hr3*16 + hc3;
                            #pragma unroll
                            for (int nt = 0; nt < 4; nt++){
                                float hbv = b2f(hB[(e3-16)*72 + nt*16 + l15]);
                                hCur[e3*72 + nt*16 + l15] = bfr(hbv + cs*kv[g][reg*4+nt]);
                            }
                        }
                    }
                }
            } else {
                if ((g == 1 || g == 2) && (lg == 1 || lg == 2)){
                    #pragma unroll
                    for (int reg = 0; reg < 4; reg++){
                        int hc3 = lg*4 + reg;
                        int e3 = hr3*16 + hc3;
                        long gn = nb + (r0+hr3)*64 + (c0+hc3);
                        #pragma unroll
                        for (int nt = 0; nt < 4; nt++){
                            float hbv = b2f(hB[(e3-16)*72 + nt*16 + l15]);
                            float fin = hbv + (0.25f/6.f)*(Ast[g-1][reg*4+nt] + kv[g][reg*4+nt]);
                            HOUT[gn*64 + nt*16 + l15] = bfr(fin);
                        }
                    }
                }
            }
        }
    }
}

// ---- head: LN + MLP + fire override (reads bf16 HX) ----
__global__ __launch_bounds__(256) void head_kernel(
    const unsigned short* __restrict__ HX, const float* __restrict__ x,
    const float* __restrict__ g_h, const float* __restrict__ bt_h,
    const float* __restrict__ Wh1, const float* __restrict__ bh1,
    const float* __restrict__ Wh2, const float* __restrict__ bh2,
    float* __restrict__ out)
{
    __shared__ __align__(16) float sm[4624];
    float* hT = sm;          // [64][68]
    float* pl = sm + 4352;   // [4][68]

    int t = threadIdx.x;
    int w = __builtin_amdgcn_readfirstlane(t >> 6);
    int lane = t & 63;
    int n0 = blockIdx.x * 64;
    int b = n0 >> 12;
    int cell0 = n0 & 4095;

    for (int e = t; e < 4096; e += 256){
        int n = e >> 6, j = e & 63;
        hT[j*68 + n] = b2f(HX[(n0+n)*64 + j]);
    }
    __syncthreads();

    float s1 = 0.f, s2 = 0.f;
    for (int j = 0; j < 64; j++){
        float v = hT[j*68 + lane];
        s1 += v; s2 += v*v;
    }
    float mean = s1*(1.f/64.f);
    float var  = s2*(1.f/64.f) - mean*mean;
    float rstd = rsqrtf(fmaxf(var, 0.f) + 1e-5f);

    float acc[16];
    #pragma unroll
    for (int kk = 0; kk < 16; kk++) acc[kk] = bh1[w*16 + kk];
    for (int j = 0; j < 64; j++){
        float v = (hT[j*68 + lane] - mean)*rstd*g_h[j] + bt_h[j];
        #pragma unroll
        for (int kk = 0; kk < 16; kk++)
            acc[kk] += v * Wh1[j*64 + w*16 + kk];
    }
    float plg = 0.f;
    #pragma unroll
    for (int kk = 0; kk < 16; kk++){
        float a = acc[kk];
        plg += (a * sigmoidf_(a)) * Wh2[w*16 + kk];
    }
    pl[w*68 + lane] = plg;
    __syncthreads();
    if (t < 64){
        float lgt = pl[0*68+t] + pl[1*68+t] + pl[2*68+t] + pl[3*68+t] + bh2[0];
        float fire = x[b*(12*NN) + cell0 + t];
        out[n0 + t] = (fire > 0.5f) ? fmaxf(lgt, 6.f) : lgt;
    }
}

extern "C" void kernel_launch(void* const* d_in, const int* in_sizes, int n_in,
                              void* d_out, int out_size, void* d_ws, size_t ws_size,
                              hipStream_t stream)
{
    const float* x       = (const float*)d_in[0];
    const float* W_enc1  = (const float*)d_in[3];
    const float* b_enc1  = (const float*)d_in[4];
    const float* W_enc2  = (const float*)d_in[5];
    const float* b_enc2  = (const float*)d_in[6];
    const float* W_gat   = (const float*)d_in[7];
    const float* att_src = (const float*)d_in[8];
    const float* att_dst = (const float*)d_in[9];
    const float* W_edge  = (const float*)d_in[10];
    const float* att_edge= (const float*)d_in[11];
    const float* b_gat   = (const float*)d_in[12];
    const float* g_f     = (const float*)d_in[13];
    const float* bt_f    = (const float*)d_in[14];
    const float* g_h     = (const float*)d_in[15];
    const float* bt_h    = (const float*)d_in[16];
    const float* W_h1    = (const float*)d_in[17];
    const float* b_h1    = (const float*)d_in[18];
    const float* W_h2    = (const float*)d_in[19];
    const float* b_h2    = (const float*)d_in[20];

    float* ws  = (float*)d_ws;
    float* CAS = ws;                  // 256
    float* CAD = ws + 256;            // 256
    float* CCE = ws + 512;            // 16
    unsigned short* AsAdT = (unsigned short*)(ws + 528);    // [16][64] bf16
    unsigned short* WT2h  = (unsigned short*)(ws + 1040);   // [64][256] bf16
    unsigned short* WT2l  = (unsigned short*)(ws + 9232);   // [64][256] bf16
    unsigned short* HXA   = (unsigned short*)(ws + 17424);  // [BN][64] bf16
    unsigned short* HXB   = (unsigned short*)(ws + 17424 + 1048576);
    float* out = (float*)d_out;

    prep_kernel<<<1, 256, 0, stream>>>(W_gat, att_src, att_dst, W_edge, att_edge,
                                       CAS, CAD, CCE, AsAdT, WT2h, WT2l);
    enc_kernel<<<512, 256, 0, stream>>>(x, W_enc1, b_enc1, W_enc2, b_enc2, HXA);

    unsigned short* hin = HXA; unsigned short* hout = HXB;
    for (int step = 0; step < 4; step++){
        step_kernel<<<512, 256, 0, stream>>>(hin, hout, x, CCE, AsAdT, WT2h, WT2l,
                                             b_gat, g_f, bt_f);
        unsigned short* tm = hin; hin = hout; hout = tm;
    }

    head_kernel<<<512, 256, 0, stream>>>(hin, x, g_h, bt_h, W_h1, b_h1, W_h2, b_h2, out);
}

// Round 13
// 685.771 us; speedup vs baseline: 3.1556x; 3.1556x over previous
//
#include <hip/hip_runtime.h>

#define NN 4096
#define BN 32768

typedef __attribute__((ext_vector_type(8))) short short8;
typedef __attribute__((ext_vector_type(4))) float f32x4;

__device__ __forceinline__ float sigmoidf_(float x){ return 1.f/(1.f+__expf(-x)); }
__device__ __forceinline__ unsigned short bfr(float f){
    unsigned int u = __float_as_uint(f);
    u += 0x7FFFu + ((u>>16)&1u);
    return (unsigned short)(u>>16);
}
__device__ __forceinline__ float b2f(unsigned short h){
    return __uint_as_float(((unsigned int)h)<<16);
}

// ---- prep: As/Ad, cE, AsAdT[16][64] bf16, WT2 hi/lo [64 j][256 khh] bf16 ----
__global__ void prep_kernel(const float* __restrict__ W_gat,
                            const float* __restrict__ att_src,
                            const float* __restrict__ att_dst,
                            const float* __restrict__ W_edge,
                            const float* __restrict__ att_edge,
                            float* __restrict__ As, float* __restrict__ Ad,
                            float* __restrict__ cE,
                            unsigned short* __restrict__ AsAdT,
                            unsigned short* __restrict__ WT2h,
                            unsigned short* __restrict__ WT2l)
{
    int t = threadIdx.x;          // 256
    int i = t >> 2, hh = t & 3;   // t = k*4+h
    float s = 0.f, d = 0.f;
    for (int j = 0; j < 64; j++){
        float w = W_gat[i*256 + hh*64 + j];
        s += w * att_src[hh*64 + j];
        d += w * att_dst[hh*64 + j];
    }
    As[t] = s;
    Ad[t] = d;
    if (t < 12){
        int e = t >> 2, h2 = t & 3;
        float cc = 0.f;
        for (int k = 0; k < 64; k++)
            cc += W_edge[e*256 + h2*64 + k] * att_edge[h2*64 + k];
        cE[h2*3 + e] = cc;
    }
    __syncthreads();
    if (t < 16){
        for (int k = 0; k < 64; k++){
            float v = (t < 4) ? As[k*4 + t] : (t < 8 ? Ad[k*4 + (t-4)] : 0.f);
            AsAdT[t*64 + k] = bfr(v);
        }
    }
    {
        int j = t >> 2, q = t & 3;
        for (int k = 0; k < 64; k++){
            float wv = W_gat[k*256 + q*64 + j];
            unsigned short hi = bfr(wv);
            WT2h[j*256 + q*64 + k] = hi;
            WT2l[j*256 + q*64 + k] = bfr(wv - b2f(hi));
        }
    }
}

// ---- encoder: block = 64 consecutive nodes, lane = node; bf16 H out ----
__global__ __launch_bounds__(256) void enc_kernel(
    const float* __restrict__ x,
    const float* __restrict__ W1, const float* __restrict__ b1,
    const float* __restrict__ W2, const float* __restrict__ b2,
    unsigned short* __restrict__ HX)
{
    __shared__ __align__(16) float sm[5168];
    float* xT  = sm;          // [12][68]
    float* t1  = sm + 816;    // [64][68]

    int t = threadIdx.x;
    int w = __builtin_amdgcn_readfirstlane(t >> 6);
    int lane = t & 63;
    int n0 = blockIdx.x * 64;
    int b = n0 >> 12;
    int cell0 = n0 & 4095;

    for (int e = t; e < 12*64; e += 256){
        int c = e >> 6, u = e & 63;
        xT[c*68 + u] = x[b*(12*NN) + c*NN + cell0 + u];
    }
    __syncthreads();

    #pragma unroll
    for (int jj = 0; jj < 16; jj++){
        int j = w*16 + jj;
        float a = b1[j];
        #pragma unroll
        for (int c = 0; c < 12; c++)
            a += xT[c*68 + lane] * W1[c*64 + j];
        t1[j*68 + lane] = a * sigmoidf_(a);
    }
    __syncthreads();

    float hk[16];
    #pragma unroll
    for (int kk = 0; kk < 16; kk++) hk[kk] = b2[w*16 + kk];
    for (int j = 0; j < 64; j++){
        float v = t1[j*68 + lane];
        #pragma unroll
        for (int kk = 0; kk < 16; kk++)
            hk[kk] += v * W2[j*64 + w*16 + kk];
    }
    int hb = (n0 + lane)*64 + w*16;
    unsigned int* dst = (unsigned int*)&HX[hb];
    #pragma unroll
    for (int p = 0; p < 8; p++)
        dst[p] = (unsigned int)bfr(hk[2*p]) | ((unsigned int)bfr(hk[2*p+1])<<16);
}

// ================== f(): one RK4 stage, 8 waves; bf16 state; coalesced writes ==================
// block = 8x8 tile + halo-1 (10x10); 512 threads; wave w: rt = w&3, hp = w>>2.
__global__ __launch_bounds__(512, 4) void f_kernel(
    const unsigned short* __restrict__ HIN,    // stage input [BN][64] bf16
    const unsigned short* __restrict__ BASE,   // step-base h [BN][64] bf16
    unsigned short* __restrict__ ACCB,         // RK4 acc [BN][64] bf16
    unsigned short* __restrict__ HOUT,         // stage output [BN][64] bf16
    const float* __restrict__ x,
    const float* __restrict__ CCE,
    const unsigned short* __restrict__ AsAdT,
    const unsigned short* __restrict__ WT2h, const unsigned short* __restrict__ WT2l,
    const float* __restrict__ b_gat, const float* __restrict__ g_f, const float* __restrict__ bt_f,
    int stage)
{
    __shared__ __align__(16) char smem[46784];
    unsigned short* hA = (unsigned short*)smem;          // [112][72] bf16
    float* aL   = (float*)(smem + 16128);                // [64 e][36]
    float* as2  = (float*)(smem + 25344);                // [112][4]
    float* ad2  = (float*)(smem + 27136);                // [112][4]
    float* x0h  = (float*)(smem + 28928);                // [112]
    float* osum = (float*)(smem + 29376);                // [64][68]
    // write-staging (aliased over dead hA / aL after compute):
    unsigned short* wbuf = (unsigned short*)smem;            // [64][72] bf16
    unsigned short* abuf = (unsigned short*)(smem + 16128);  // [64][72] bf16

    int t = threadIdx.x;
    int w = __builtin_amdgcn_readfirstlane(t >> 6);      // wave 0..7
    int rt = w & 3, hp = w >> 2;
    int lane = t & 63;
    int l15 = lane & 15, lg = lane >> 4;
    int blk = blockIdx.x;
    int b = blk & 7, tile = blk >> 3;      // batch pinned to XCD
    int tr = tile >> 3, tc = tile & 7;
    int r0 = tr*8 - 1, c0 = tc*8 - 1;
    int nb = b*NN;
    int xb = b*(12*NN);

    const int DYI[8] = {-1,-1,-1,0,0,1,1,1};
    const int DXI[8] = {-1,0,1,-1,1,-1,0,1};
    const float s2c = 0.70710678f;
    const float DXN[8] = {-s2c,0.f,s2c,-1.f,1.f,-s2c,0.f,s2c};
    const float DYN[8] = {-s2c,-1.f,-s2c,0.f,0.f,s2c,1.f,s2c};

    // ---- phase 1: stage halo (bf16 copy) + zero pad + x0h ----
    for (int u = t; u < 800; u += 512){
        int m = u >> 3, k8 = u & 7;
        int hr = m/10, hc = m - hr*10;
        int r = min(63,max(0,r0+hr)), c = min(63,max(0,c0+hc));
        *(uint4*)&hA[m*72 + k8*8] = *(const uint4*)&HIN[(long)(nb + r*64 + c)*64 + k8*8];
    }
    for (int u = t; u < 432; u += 512)
        ((unsigned int*)(smem + 14400))[u] = 0u;
    if (t < 112){
        float v = 0.f;
        if (t < 100){
            int hr = t/10, hc = t - hr*10;
            int r = min(63,max(0,r0+hr)), c = min(63,max(0,c0+hc));
            v = x[xb + r*64 + c];
        }
        x0h[t] = v;
    }
    __syncthreads();

    // ---- phase 2: as/ad via MFMA (wave w -> row-tile w, 7 tiles) ----
    if (w < 7){
        f32x4 acc = {0.f,0.f,0.f,0.f};
        #pragma unroll
        for (int kt = 0; kt < 2; kt++){
            short8 afr  = *(const short8*)&AsAdT[l15*64 + kt*32 + lg*8];
            short8 bfrg = *(const short8*)&hA[(w*16+l15)*72 + kt*32 + lg*8];
            acc = __builtin_amdgcn_mfma_f32_16x16x32_bf16(afr, bfrg, acc, 0,0,0);
        }
        int m = w*16 + l15;
        if (lg == 0)      *(float4*)&as2[m*4] = make_float4(acc[0],acc[1],acc[2],acc[3]);
        else if (lg == 1) *(float4*)&ad2[m*4] = make_float4(acc[0],acc[1],acc[2],acc[3]);
    }
    __syncthreads();

    // ---- phase 3: alpha (threads 0..255: e = t&63, head = t>>6) ----
    if (t < 256){
        int e = t & 63, hh = t >> 6;
        int er = e >> 3, ec = e & 7;
        int gr = tr*8 + er, gc = tc*8 + ec;
        int me = (er+1)*10 + (ec+1);
        float adv = ad2[me*4 + hh];
        float x0n = x0h[me];
        float ce0 = CCE[hh*3+0], ce1 = CCE[hh*3+1], ce2 = CCE[hh*3+2];
        float al[8]; float mx = -1e30f;
        #pragma unroll
        for (int o = 0; o < 8; o++){
            int mr = gr - DYI[o], mc = gc - DXI[o];
            bool vld = (mr>=0)&&(mr<64)&&(mc>=0)&&(mc<64);
            int hm = me - DYI[o]*10 - DXI[o];
            float a = as2[hm*4+hh] + adv + ce0*DXN[o] + ce1*DYN[o]
                    + ce2*(x0n - x0h[hm]);
            a = (a >= 0.f) ? a : 0.2f*a;
            al[o] = vld ? a : -1e30f;
            mx = fmaxf(mx, al[o]);
        }
        float z = 0.f;
        #pragma unroll
        for (int o = 0; o < 8; o++){
            float p = (al[o] > -1e29f) ? __expf(al[o]-mx) : 0.f;
            al[o] = p; z += p;
        }
        float zi = 1.f/(z + 1e-16f);
        #pragma unroll
        for (int o = 0; o < 8; o++)
            aL[e*36 + o*4 + hh] = al[o]*zi;
    }
    __syncthreads();

    // ---- phase 4: per-lane mix for this wave's head-pair (G[4][8]) ----
    int e2 = rt*16 + l15;
    int me2 = ((e2>>3)+1)*10 + ((e2&7)+1);
    float G[4][8];
    #pragma unroll
    for (int kt = 0; kt < 4; kt++)
        #pragma unroll
        for (int i = 0; i < 8; i++) G[kt][i] = 0.f;
    #pragma unroll
    for (int o = 0; o < 8; o++){
        int hm = me2 - DYI[o]*10 - DXI[o];
        float2 ao = *(const float2*)&aL[e2*36 + o*4 + hp*2];  // this pair's 2 heads
        const unsigned short* hp8 = &hA[hm*72 + lg*8];
        short8 v0 = *(const short8*)&hp8[0];
        short8 v1 = *(const short8*)&hp8[32];
        #pragma unroll
        for (int i = 0; i < 8; i++){
            float f0 = b2f((unsigned short)v0[i]);
            float f1 = b2f((unsigned short)v1[i]);
            G[0][i] += ao.x*f0;  G[1][i] += ao.x*f1;
            G[2][i] += ao.y*f0;  G[3][i] += ao.y*f1;
        }
    }

    // ---- phase 5: GEMM quarter (kt = hp*4..hp*4+3, hi+lo) ----
    f32x4 oacc[4];
    #pragma unroll
    for (int nt = 0; nt < 4; nt++) oacc[nt] = (f32x4){0.f,0.f,0.f,0.f};
    #pragma unroll
    for (int ktl = 0; ktl < 4; ktl++){
        short8 afr;
        #pragma unroll
        for (int i = 0; i < 8; i++) afr[i] = (short)bfr(G[ktl][i]);
        int kcol = (hp*4 + ktl)*32 + lg*8;
        #pragma unroll
        for (int nt = 0; nt < 4; nt++){
            short8 bh = *(const short8*)&WT2h[(nt*16+l15)*256 + kcol];
            oacc[nt] = __builtin_amdgcn_mfma_f32_16x16x32_bf16(afr, bh, oacc[nt], 0,0,0);
        }
        #pragma unroll
        for (int nt = 0; nt < 4; nt++){
            short8 bl = *(const short8*)&WT2l[(nt*16+l15)*256 + kcol];
            oacc[nt] = __builtin_amdgcn_mfma_f32_16x16x32_bf16(afr, bl, oacc[nt], 0,0,0);
        }
    }

    // ---- cross-pair reduce: hp0 writes osum ----
    if (hp == 0){
        #pragma unroll
        for (int nt = 0; nt < 4; nt++)
            #pragma unroll
            for (int reg = 0; reg < 4; reg++)
                osum[(rt*16 + lg*4 + reg)*68 + nt*16 + l15] = oacc[nt][reg];
    }
    __syncthreads();

    // ---- hp1: epilogue compute into registers (reads hA/osum/BASE/ACCB) ----
    float hnR[16], avR[16];
    if (hp == 1){
        float bg[4], gf[4], bf_[4];
        #pragma unroll
        for (int nt = 0; nt < 4; nt++){
            int j = nt*16 + l15;
            bg[nt] = b_gat[j]; gf[nt] = g_f[j]; bf_[nt] = bt_f[j];
        }
        #pragma unroll
        for (int reg = 0; reg < 4; reg++){
            int e3 = rt*16 + lg*4 + reg;
            float vv[4];
            float s1 = 0.f, s2 = 0.f;
            #pragma unroll
            for (int nt = 0; nt < 4; nt++){
                float v = (oacc[nt][reg] + osum[e3*68 + nt*16 + l15])*0.25f + bg[nt];
                vv[nt] = v; s1 += v; s2 += v*v;
            }
            s1 += __shfl_xor(s1,1); s2 += __shfl_xor(s2,1);
            s1 += __shfl_xor(s1,2); s2 += __shfl_xor(s2,2);
            s1 += __shfl_xor(s1,4); s2 += __shfl_xor(s2,4);
            s1 += __shfl_xor(s1,8); s2 += __shfl_xor(s2,8);
            float mean = s1*(1.f/64.f);
            float var  = s2*(1.f/64.f) - mean*mean;
            float rstd = rsqrtf(fmaxf(var,0.f) + 1e-5f);
            int me3 = ((e3>>3)+1)*10 + ((e3&7)+1);
            long gn = nb + (tr*8 + (e3>>3))*64 + tc*8 + (e3&7);
            #pragma unroll
            for (int nt = 0; nt < 4; nt++){
                int j = nt*16 + l15;
                float y = (vv[nt]-mean)*rstd*gf[nt] + bf_[nt];
                float kv = y * sigmoidf_(y);
                float hold = (stage == 0) ? b2f(hA[me3*72 + j])
                                          : b2f(BASE[gn*64 + j]);
                float hn, av = 0.f;
                if (stage == 0){
                    av = kv;                               hn = hold + 0.125f*kv;
                } else if (stage == 1){
                    av = b2f(ACCB[gn*64+j]) + 2.f*kv;      hn = hold + 0.125f*kv;
                } else if (stage == 2){
                    av = b2f(ACCB[gn*64+j]) + 2.f*kv;      hn = hold + 0.25f*kv;
                } else {
                    hn = hold + (0.25f/6.f)*(b2f(ACCB[gn*64+j]) + kv);
                }
                hnR[reg*4+nt] = hn;
                avR[reg*4+nt] = av;
            }
        }
    }
    __syncthreads();   // all hA/osum reads complete

    // ---- hp1: write staging buffers (over dead hA/aL) ----
    if (hp == 1){
        #pragma unroll
        for (int reg = 0; reg < 4; reg++){
            int e3 = rt*16 + lg*4 + reg;
            #pragma unroll
            for (int nt = 0; nt < 4; nt++){
                int j = nt*16 + l15;
                wbuf[e3*72 + j] = bfr(hnR[reg*4+nt]);
                if (stage < 3) abuf[e3*72 + j] = bfr(avR[reg*4+nt]);
            }
        }
    }
    __syncthreads();

    // ---- cooperative full-line copy-out (1KB contiguous per wave) ----
    {
        int node = t >> 3, ch = t & 7;
        long gn = nb + (tr*8 + (node>>3))*64 + tc*8 + (node&7);
        *(uint4*)&HOUT[gn*64 + ch*8] = *(const uint4*)&wbuf[node*72 + ch*8];
        if (stage < 3)
            *(uint4*)&ACCB[gn*64 + ch*8] = *(const uint4*)&abuf[node*72 + ch*8];
    }
}

// ---- head: LN + MLP + fire override (bf16 input) ----
__global__ __launch_bounds__(256) void head_kernel(
    const unsigned short* __restrict__ HX, const float* __restrict__ x,
    const float* __restrict__ g_h, const float* __restrict__ bt_h,
    const float* __restrict__ Wh1, const float* __restrict__ bh1,
    const float* __restrict__ Wh2, const float* __restrict__ bh2,
    float* __restrict__ out)
{
    __shared__ __align__(16) float sm[4624];
    float* hT = sm;          // [64][68]
    float* pl = sm + 4352;   // [4][68]

    int t = threadIdx.x;
    int w = __builtin_amdgcn_readfirstlane(t >> 6);
    int lane = t & 63;
    int n0 = blockIdx.x * 64;
    int b = n0 >> 12;
    int cell0 = n0 & 4095;

    for (int e = t; e < 4096; e += 256){
        int n = e >> 6, j = e & 63;
        hT[j*68 + n] = b2f(HX[(n0+n)*64 + j]);
    }
    __syncthreads();

    float s1 = 0.f, s2 = 0.f;
    for (int j = 0; j < 64; j++){
        float v = hT[j*68 + lane];
        s1 += v; s2 += v*v;
    }
    float mean = s1*(1.f/64.f);
    float var  = s2*(1.f/64.f) - mean*mean;
    float rstd = rsqrtf(fmaxf(var, 0.f) + 1e-5f);

    float acc[16];
    #pragma unroll
    for (int kk = 0; kk < 16; kk++) acc[kk] = bh1[w*16 + kk];
    for (int j = 0; j < 64; j++){
        float v = (hT[j*68 + lane] - mean)*rstd*g_h[j] + bt_h[j];
        #pragma unroll
        for (int kk = 0; kk < 16; kk++)
            acc[kk] += v * Wh1[j*64 + w*16 + kk];
    }
    float plg = 0.f;
    #pragma unroll
    for (int kk = 0; kk < 16; kk++){
        float a = acc[kk];
        plg += (a * sigmoidf_(a)) * Wh2[w*16 + kk];
    }
    pl[w*68 + lane] = plg;
    __syncthreads();
    if (t < 64){
        float lgt = pl[0*68+t] + pl[1*68+t] + pl[2*68+t] + pl[3*68+t] + bh2[0];
        float fire = x[b*(12*NN) + cell0 + t];
        out[n0 + t] = (fire > 0.5f) ? fmaxf(lgt, 6.f) : lgt;
    }
}

extern "C" void kernel_launch(void* const* d_in, const int* in_sizes, int n_in,
                              void* d_out, int out_size, void* d_ws, size_t ws_size,
                              hipStream_t stream)
{
    const float* x       = (const float*)d_in[0];
    const float* W_enc1  = (const float*)d_in[3];
    const float* b_enc1  = (const float*)d_in[4];
    const float* W_enc2  = (const float*)d_in[5];
    const float* b_enc2  = (const float*)d_in[6];
    const float* W_gat   = (const float*)d_in[7];
    const float* att_src = (const float*)d_in[8];
    const float* att_dst = (const float*)d_in[9];
    const float* W_edge  = (const float*)d_in[10];
    const float* att_edge= (const float*)d_in[11];
    const float* b_gat   = (const float*)d_in[12];
    const float* g_f     = (const float*)d_in[13];
    const float* bt_f    = (const float*)d_in[14];
    const float* g_h     = (const float*)d_in[15];
    const float* bt_h    = (const float*)d_in[16];
    const float* W_h1    = (const float*)d_in[17];
    const float* b_h1    = (const float*)d_in[18];
    const float* W_h2    = (const float*)d_in[19];
    const float* b_h2    = (const float*)d_in[20];

    float* ws  = (float*)d_ws;
    float* CAS = ws;                  // 256
    float* CAD = ws + 256;            // 256
    float* CCE = ws + 512;            // 16
    unsigned short* AsAdT = (unsigned short*)(ws + 528);     // [16][64] bf16
    unsigned short* WT2h  = (unsigned short*)(ws + 1040);    // [64][256] bf16
    unsigned short* WT2l  = (unsigned short*)(ws + 9232);    // [64][256] bf16
    unsigned short* B0    = (unsigned short*)(ws + 17424);   // [BN][64] bf16
    unsigned short* B1    = (unsigned short*)(ws + 1066000); // [BN][64] bf16
    unsigned short* B2    = (unsigned short*)(ws + 2114576); // [BN][64] bf16
    unsigned short* ACCB  = (unsigned short*)(ws + 3163152); // [BN][64] bf16
    float* out = (float*)d_out;

    prep_kernel<<<1, 256, 0, stream>>>(W_gat, att_src, att_dst, W_edge, att_edge,
                                       CAS, CAD, CCE, AsAdT, WT2h, WT2l);
    enc_kernel<<<512, 256, 0, stream>>>(x, W_enc1, b_enc1, W_enc2, b_enc2, B0);

    unsigned short* Bb = B0;   // step base
    unsigned short* C1 = B1;   // scratch
    unsigned short* C2 = B2;   // scratch
    for (int step = 0; step < 4; step++){
        f_kernel<<<512, 512, 0, stream>>>(Bb, Bb, ACCB, C1, x, CCE, AsAdT, WT2h, WT2l,
                                          b_gat, g_f, bt_f, 0);
        f_kernel<<<512, 512, 0, stream>>>(C1, Bb, ACCB, C2, x, CCE, AsAdT, WT2h, WT2l,
                                          b_gat, g_f, bt_f, 1);
        f_kernel<<<512, 512, 0, stream>>>(C2, Bb, ACCB, C1, x, CCE, AsAdT, WT2h, WT2l,
                                          b_gat, g_f, bt_f, 2);
        f_kernel<<<512, 512, 0, stream>>>(C1, Bb, ACCB, C2, x, CCE, AsAdT, WT2h, WT2l,
                                          b_gat, g_f, bt_f, 3);
        unsigned short* newBb = C2;
        unsigned short* newC1 = Bb;
        unsigned short* newC2 = C1;
        Bb = newBb; C1 = newC1; C2 = newC2;
    }

    head_kernel<<<512, 256, 0, stream>>>(Bb, x, g_h, bt_h, W_h1, b_h1, W_h2, b_h2, out);
}